// Round 3
// baseline (3482.687 us; speedup 1.0000x reference)
//
#include <hip/hip_runtime.h>

// LSTM_3813930958978: T=512, B=64, I=1024, H=1024, gate order i,f,g,o.
//
// R1: h-path via global_load_lds DMA (SC0|SC1, MALL-coherent), fences
//     removed, poll relay. 8490 -> 4845 us.
// R2: x-path DMA-staged. 4845 -> 3290 us. FETCH still 533MB = per-XCD
//     x broadcast (8 XCD x 64MB) -> x-GEMM doesn't belong in the loop.
// R3 (this round): hoist the x-GEMM out of the recurrence entirely.
//  - xg_gemm: persistent-weight GEMM (256 blocks, 4-wave K-split,
//    cross-t prefetch, XCD-aware block mapping so same-t blocks share
//    L2) precomputes xg[t] = x_t @ W_ih^T + bias for ALL t.
//  - lstm_persist: h-only. 4 waves split W_hh K 4-ways (bfrag[8][2]).
//    h lives in a column-blocked layout [cb][64][8] bf16: each block
//    stores ONE contiguous 1KB slice (coalesced MALL write-through),
//    each wave DMA-reads ONE contiguous 32KB span (linear, no swizzle).
//    xg slice (8KB/block/step, block-private, L2-cacheable) is loaded
//    BEFORE the epoch poll -> latency fully hidden.
//  - barrier #1 is a raw s_barrier (no vmcnt(0) drain). sync #2 +
//    2-level arrival tree unchanged (one variable at a time).
//  - xg stored f32 if ws >= 640MB else bf16 (runtime check).

#define TT 512
#define BB 64
#define II 1024
#define HHH 1024
#define G4 4096
#define NBLK 128
#define HPB 8

typedef __attribute__((ext_vector_type(8))) short short8;
typedef __attribute__((ext_vector_type(4))) float f32x4;
typedef __attribute__((ext_vector_type(4))) int i32x4;

typedef __attribute__((address_space(1))) const void gvoid;
typedef __attribute__((address_space(3))) void lvoid;

__device__ __forceinline__ short8 load_frag(const unsigned short* p) {
  i32x4 v = *(const i32x4*)p;
  return __builtin_bit_cast(short8, v);
}

__device__ __forceinline__ unsigned short f2bf(float f) {
  unsigned u = __builtin_bit_cast(unsigned, f);
  u = (u + 0x7FFFu + ((u >> 16) & 1u)) >> 16;
  return (unsigned short)u;
}

__device__ __forceinline__ float sigm(float x) {
  return 1.0f / (1.0f + __expf(-x));
}
__device__ __forceinline__ float tanh_f(float x) {
  return 2.0f / (1.0f + __expf(-2.0f * x)) - 1.0f;
}

// ---- conversion kernels ------------------------------------------------
__global__ void cvt_bf16(const float* __restrict__ s,
                         unsigned short* __restrict__ d, int n4) {
  int stride = gridDim.x * blockDim.x;
  for (int i = blockIdx.x * blockDim.x + threadIdx.x; i < n4; i += stride) {
    f32x4 v = *(const f32x4*)(s + 4 * i);
    unsigned lo = (unsigned)f2bf(v[0]) | ((unsigned)f2bf(v[1]) << 16);
    unsigned hi = (unsigned)f2bf(v[2]) | ((unsigned)f2bf(v[3]) << 16);
    uint2 u; u.x = lo; u.y = hi;
    *(uint2*)(d + 4 * i) = u;
  }
}

__global__ void bias_sum(const float* __restrict__ a,
                         const float* __restrict__ b,
                         float* __restrict__ o) {
  int i = blockIdx.x * blockDim.x + threadIdx.x;
  if (i < G4) o[i] = a[i] + b[i];
}

// ---- xg precompute: xg[cb][t][64][32] = x_t @ W_ih^T + bias -----------
// 256 blocks x 256 threads, 1 block/CU. bid -> (cb, t-half) mapped so the
// 32 blocks of an XCD (bid%8) form 16 cbs x 2 t-streams -> same-t x tiles
// are L2-shared (working set 2 x 128KB << 4MB).
__global__ __launch_bounds__(256, 1) void xg_gemm(
    const unsigned short* __restrict__ xb,    // [T][64][1024] bf16
    const unsigned short* __restrict__ wih,   // [4096][1024] bf16
    const float* __restrict__ bsum,           // [4096] f32
    char* __restrict__ xg, int xg32)
{
  const int tid = threadIdx.x;
  const int wid = tid >> 6;
  const int lane = tid & 63;
  const int ln15 = lane & 15;
  const int quad = lane >> 4;
  const int bid = blockIdx.x;
  const int cb = (bid & 7) | ((bid >> 4) << 3);   // 0..127
  const int t0 = ((bid >> 3) & 1) * 256;          // t-half
  const int hc0 = cb * HPB;
  const int koff = wid * 256;                     // 4-way K split

  __shared__ float red[4][64][36];
  __shared__ __align__(16) short xstage[4][2][4096];  // [wave][buf][8KB]

  // persistent W_ih B-fragments: per wave K=256 -> bfrag[8][2]
  short8 bfrag[8][2];
#pragma unroll
  for (int nt = 0; nt < 2; ++nt) {
    int n = nt * 16 + ln15;
    int grow = (n >> 3) * 1024 + hc0 + (n & 7);
#pragma unroll
    for (int kc = 0; kc < 8; ++kc) {
      int k = koff + kc * 32 + quad * 8;
      bfrag[kc][nt] = load_frag(wih + grow * 1024 + k);
    }
  }

  const int eb = tid >> 2;
  const int erp = tid & 3;
  float bsv[4][2];
#pragma unroll
  for (int q = 0; q < 4; ++q)
#pragma unroll
    for (int rr = 0; rr < 2; ++rr)
      bsv[q][rr] = bsum[q * 1024 + hc0 + erp * 2 + rr];

  // x staging constants (R2-proven pattern, row-swizzled global source)
  const unsigned xrow = (unsigned)(lane >> 3);
  const unsigned xlane = xrow * 2048u + (unsigned)wid * 512u +
                         (((unsigned)(lane & 7) ^ xrow) * 16u);
  const unsigned lsw = (unsigned)(ln15 & 7) << 4;
  const unsigned q16 = (unsigned)quad * 16u;

  f32x4 acc[4][2];

  auto stage_x = [&](int t, int ck, int buf) {
    short* lb = &xstage[wid][buf][0];
    const char* gt = (const char*)xb + (size_t)t * 131072u;
#pragma unroll
    for (int j = 0; j < 8; ++j) {
      unsigned off = xlane + (unsigned)j * 16384u + (unsigned)ck * 128u;
      __builtin_amdgcn_global_load_lds((gvoid*)(gt + off),
                                       (lvoid*)(lb + j * 512), 16, 0, 0);
    }
  };
  auto comp_x = [&](int ck, int buf) {
    const char* lb = (const char*)&xstage[wid][buf][0];
#pragma unroll
    for (int kl = 0; kl < 2; ++kl) {
      int kc = ck * 2 + kl;
#pragma unroll
      for (int m = 0; m < 4; ++m) {
        unsigned loff = (unsigned)m * 2048u + (unsigned)ln15 * 128u +
                        (((unsigned)kl * 64u + q16) ^ lsw);
        short8 a = *(const short8*)(lb + loff);
        acc[m][0] = __builtin_amdgcn_mfma_f32_16x16x32_bf16(
            a, bfrag[kc][0], acc[m][0], 0, 0, 0);
        acc[m][1] = __builtin_amdgcn_mfma_f32_16x16x32_bf16(
            a, bfrag[kc][1], acc[m][1], 0, 0, 0);
      }
    }
  };

  stage_x(t0, 0, 0);
  stage_x(t0, 1, 1);

#pragma unroll 1
  for (int ti = 0; ti < 256; ++ti) {
    const int t = t0 + ti;
#pragma unroll
    for (int m = 0; m < 4; ++m)
#pragma unroll
      for (int nt = 0; nt < 2; ++nt)
        acc[m][nt] = (f32x4){0.0f, 0.0f, 0.0f, 0.0f};

    asm volatile("s_waitcnt vmcnt(8)" ::: "memory");
    comp_x(0, 0);
    asm volatile("s_waitcnt lgkmcnt(0)" ::: "memory");
    stage_x(t, 2, 0);
    asm volatile("s_waitcnt vmcnt(8)" ::: "memory");
    comp_x(1, 1);
    asm volatile("s_waitcnt lgkmcnt(0)" ::: "memory");
    stage_x(t, 3, 1);
    asm volatile("s_waitcnt vmcnt(8)" ::: "memory");
    comp_x(2, 0);
    asm volatile("s_waitcnt vmcnt(0)" ::: "memory");
    comp_x(3, 1);

    // dump partials
#pragma unroll
    for (int m = 0; m < 4; ++m)
#pragma unroll
      for (int nt = 0; nt < 2; ++nt)
#pragma unroll
        for (int p = 0; p < 4; ++p)
          red[wid][m * 16 + quad * 4 + p][nt * 16 + ln15] = acc[m][nt][p];

    asm volatile("s_waitcnt lgkmcnt(0)" ::: "memory");
    __builtin_amdgcn_s_barrier();

    // reduce + bias, write xg slice
    size_t xoff = (((size_t)cb * 512 + (size_t)t) * 64 + (size_t)eb) * 32 +
                  (size_t)(erp * 2);
    float s[4][2];
#pragma unroll
    for (int rr = 0; rr < 2; ++rr) {
      int r = erp * 2 + rr;
#pragma unroll
      for (int q = 0; q < 4; ++q) {
        int col = q * 8 + r;
        s[q][rr] = red[0][eb][col] + red[1][eb][col] + red[2][eb][col] +
                   red[3][eb][col] + bsv[q][rr];
      }
    }
    if (xg32) {
      float* xp = (float*)xg + xoff;
#pragma unroll
      for (int q = 0; q < 4; ++q) {
        float2 v; v.x = s[q][0]; v.y = s[q][1];
        *(float2*)(xp + q * 8) = v;
      }
    } else {
      unsigned short* xp = (unsigned short*)xg + xoff;
#pragma unroll
      for (int q = 0; q < 4; ++q) {
        unsigned u = (unsigned)f2bf(s[q][0]) | ((unsigned)f2bf(s[q][1]) << 16);
        *(unsigned*)(xp + q * 8) = u;
      }
    }

    // cross-t prefetch (in-order vmcnt: stores retire before these loads)
    if (ti < 255) {
      stage_x(t + 1, 0, 0);
      stage_x(t + 1, 1, 1);
    }
    asm volatile("s_waitcnt lgkmcnt(0)" ::: "memory");
    __builtin_amdgcn_s_barrier();
  }
}

// ---- persistent LSTM recurrence ---------------------------------------
// h layout: blocked [2][128 cb][64 row][8 col] bf16. Block cb's store is
// one contiguous 1KB region; wave w reads col-blocks [32w,32w+32) = one
// contiguous 32KB span.
// barrier_mem (uint words): [0]=epoch, [32]=root, [64+32g]=leaf g.
__global__ __launch_bounds__(256, 1) void lstm_persist(
    const unsigned short* __restrict__ whh,   // [4096][1024] bf16
    const char* __restrict__ xg, int xg32,    // [128][512][64][32]
    unsigned short* __restrict__ hbuf,        // 2 x [128][64][8] bf16
    unsigned int* __restrict__ barrier_mem,   // zeroed
    float* __restrict__ out)                  // [64][1024] f32
{
  const int tid = threadIdx.x;
  const int wid = tid >> 6;
  const int lane = tid & 63;
  const int ln15 = lane & 15;
  const int quad = lane >> 4;
  const int cb = blockIdx.x;
  const int hc0 = cb * HPB;
  const int koff = wid * 256;        // 4-way K split over W_hh

  unsigned int* epoch = barrier_mem;
  unsigned int* root = barrier_mem + 32;
  unsigned int* leaf = barrier_mem + 64 + (cb >> 4) * 32;

  __shared__ float red[4][64][36];
  __shared__ __align__(16) short hstage[4][2][4096];  // [wave][buf][8KB]
  __shared__ unsigned ready;

  // persistent W_hh B-fragments
  short8 bfrag[8][2];
#pragma unroll
  for (int nt = 0; nt < 2; ++nt) {
    int n = nt * 16 + ln15;
    int grow = (n >> 3) * 1024 + hc0 + (n & 7);
#pragma unroll
    for (int kc = 0; kc < 8; ++kc) {
      int k = koff + kc * 32 + quad * 8;
      bfrag[kc][nt] = load_frag(whh + grow * 1024 + k);
    }
  }

  const int eb = tid >> 2;
  const int erp = tid & 3;
  const size_t xbase0 = (((size_t)cb * 512) * 64 + (size_t)eb) * 32 +
                        (size_t)(erp * 2);

  if (tid == 0) ready = 0u;
  __syncthreads();

  float cst[2] = {0.0f, 0.0f};
  f32x4 acc[4][2];

  auto stage = [&](const char* gsrc, int ck, int buf) {
    short* lb = &hstage[wid][buf][0];
    const char* gs = gsrc + wid * 32768 + ck * 8192 + (unsigned)lane * 16u;
#pragma unroll
    for (int j = 0; j < 8; ++j) {
      __builtin_amdgcn_global_load_lds((gvoid*)(gs + j * 1024),
                                       (lvoid*)(lb + j * 512),
                                       16, 0, 0x11);  // SC0|SC1
    }
  };
  auto comp = [&](int ck, int buf) {
    const char* lb = (const char*)&hstage[wid][buf][0];
#pragma unroll
    for (int kl = 0; kl < 2; ++kl) {
      int kc = ck * 2 + kl;
#pragma unroll
      for (int m = 0; m < 4; ++m) {
        unsigned loff = (unsigned)(kl * 4 + quad) * 1024u +
                        (unsigned)(m * 16 + ln15) * 16u;
        short8 a = *(const short8*)(lb + loff);
        acc[m][0] = __builtin_amdgcn_mfma_f32_16x16x32_bf16(
            a, bfrag[kc][0], acc[m][0], 0, 0, 0);
        acc[m][1] = __builtin_amdgcn_mfma_f32_16x16x32_bf16(
            a, bfrag[kc][1], acc[m][1], 0, 0, 0);
      }
    }
  };

#pragma unroll 1
  for (int t = 0; t < TT; ++t) {
    // xg slice load: independent of the epoch -> issue BEFORE the poll.
    float xgv[4][2];
    if (xg32) {
      const float* xp = (const float*)xg + xbase0 + (size_t)t * 2048u;
#pragma unroll
      for (int q = 0; q < 4; ++q) {
        float2 v = *(const float2*)(xp + q * 8);
        xgv[q][0] = v.x; xgv[q][1] = v.y;
      }
    } else {
      const unsigned short* xp =
          (const unsigned short*)xg + xbase0 + (size_t)t * 2048u;
#pragma unroll
      for (int q = 0; q < 4; ++q) {
        unsigned u = *(const unsigned*)(xp + q * 8);
        xgv[q][0] = __builtin_bit_cast(float, u << 16);
        xgv[q][1] = __builtin_bit_cast(float, u & 0xffff0000u);
      }
    }

#pragma unroll
    for (int m = 0; m < 4; ++m)
#pragma unroll
      for (int nt = 0; nt < 2; ++nt)
        acc[m][nt] = (f32x4){0.0f, 0.0f, 0.0f, 0.0f};

    if (t) {
      // poll: wave0 lane0 on the MALL epoch word, others on LDS relay
      if (wid == 0) {
        if (lane == 0) {
          while (__hip_atomic_load(epoch, __ATOMIC_RELAXED,
                                   __HIP_MEMORY_SCOPE_AGENT) < (unsigned)t)
            __builtin_amdgcn_s_sleep(1);
          __hip_atomic_store(&ready, (unsigned)t, __ATOMIC_RELAXED,
                             __HIP_MEMORY_SCOPE_WORKGROUP);
        }
      } else {
        while (__hip_atomic_load(&ready, __ATOMIC_RELAXED,
                                 __HIP_MEMORY_SCOPE_WORKGROUP) < (unsigned)t)
          __builtin_amdgcn_s_sleep(1);
      }

      const char* gsrc = (const char*)(hbuf + (t & 1) * 65536);
      stage(gsrc, 0, 0);
      stage(gsrc, 1, 1);
      asm volatile("s_waitcnt vmcnt(8)" ::: "memory");
      comp(0, 0);
      asm volatile("s_waitcnt lgkmcnt(0)" ::: "memory");
      stage(gsrc, 2, 0);
      asm volatile("s_waitcnt vmcnt(8)" ::: "memory");
      comp(1, 1);
      asm volatile("s_waitcnt lgkmcnt(0)" ::: "memory");
      stage(gsrc, 3, 1);
      asm volatile("s_waitcnt vmcnt(8)" ::: "memory");
      comp(2, 0);
      asm volatile("s_waitcnt vmcnt(0)" ::: "memory");
      comp(3, 1);
    }
    // t==0: h0 = 0 -> gates are xg only; acc stays zero.

#pragma unroll
    for (int m = 0; m < 4; ++m)
#pragma unroll
      for (int nt = 0; nt < 2; ++nt)
#pragma unroll
        for (int p = 0; p < 4; ++p)
          red[wid][m * 16 + quad * 4 + p][nt * 16 + ln15] = acc[m][nt][p];

    asm volatile("s_waitcnt lgkmcnt(0)" ::: "memory");
    __builtin_amdgcn_s_barrier();   // (#1) raw: no vmcnt drain needed here

    float hv[2];
#pragma unroll
    for (int rr = 0; rr < 2; ++rr) {
      int r = erp * 2 + rr;
      float g[4];
#pragma unroll
      for (int q = 0; q < 4; ++q) {
        int col = q * 8 + r;
        g[q] = red[0][eb][col] + red[1][eb][col] + red[2][eb][col] +
               red[3][eb][col] + xgv[q][rr];
      }
      float ig = sigm(g[0]);
      float fg = sigm(g[1]);
      float gg = tanh_f(g[2]);
      float og = sigm(g[3]);
      float c = fg * cst[rr] + ig * gg;
      cst[rr] = c;
      hv[rr] = og * tanh_f(c);
    }
    unsigned hpack = (unsigned)f2bf(hv[0]) | ((unsigned)f2bf(hv[1]) << 16);
    // blocked layout: block's 1KB slice, coalesced agent-scope store
    __hip_atomic_store(
        (unsigned*)(hbuf + ((t + 1) & 1) * 65536 + cb * 512 + eb * 8 +
                    erp * 2),
        hpack, __ATOMIC_RELAXED, __HIP_MEMORY_SCOPE_AGENT);

    if (t == TT - 1) {
      float2 o2; o2.x = hv[0]; o2.y = hv[1];
      *(float2*)(out + eb * HHH + hc0 + erp * 2) = o2;
    }

    __syncthreads();   // (#2) drains h stores (vmcnt 0) before arrival

    if (t < TT - 1 && tid == 0) {
      unsigned old = atomicAdd(leaf, 1u);
      if (old == (unsigned)t * 16u + 15u) {
        unsigned old2 = atomicAdd(root, 1u);
        if (old2 == (unsigned)t * 8u + 7u)
          atomicExch(epoch, (unsigned)(t + 1));
      }
    }
  }
}

// ---- launcher ----------------------------------------------------------
extern "C" void kernel_launch(void* const* d_in, const int* in_sizes, int n_in,
                              void* d_out, int out_size, void* d_ws,
                              size_t ws_size, hipStream_t stream) {
  (void)in_sizes; (void)n_in; (void)out_size;
  const float* x   = (const float*)d_in[0];
  const float* wih = (const float*)d_in[1];
  const float* whh = (const float*)d_in[2];
  const float* bih = (const float*)d_in[3];
  const float* bhh = (const float*)d_in[4];

  char* ws = (char*)d_ws;
  // workspace layout (bytes):
  //   [0, 4096)          barrier counters
  //   [4096, +256KiB)    h double buffer (2 x 128x64x8 bf16, blocked)
  //   [1MiB, 9MiB)       W_ih bf16
  //   [9MiB, 17MiB)      W_hh bf16
  //   [17MiB, +16KiB)    bias sum f32
  //   [18MiB, 82MiB)     x bf16
  //   [96MiB, ...)       xg: f32 512MiB if ws fits, else bf16 256MiB
  unsigned int*   bar  = (unsigned int*)(ws);
  unsigned short* hb   = (unsigned short*)(ws + 4096);
  unsigned short* wihb = (unsigned short*)(ws + (1ull << 20));
  unsigned short* whhb = (unsigned short*)(ws + (9ull << 20));
  float*          bs   = (float*)(ws + (17ull << 20));
  unsigned short* xb   = (unsigned short*)(ws + (18ull << 20));
  char*           xg   = ws + (96ull << 20);
  int xg32 = (ws_size >= (640ull << 20)) ? 1 : 0;

  hipMemsetAsync(ws, 0, 4096, stream);

  cvt_bf16<<<2048, 256, 0, stream>>>(x, xb, (TT * BB * II) / 4);
  cvt_bf16<<<1024, 256, 0, stream>>>(wih, wihb, (G4 * II) / 4);
  cvt_bf16<<<1024, 256, 0, stream>>>(whh, whhb, (G4 * HHH) / 4);
  bias_sum<<<16, 256, 0, stream>>>(bih, bhh, bs);

  xg_gemm<<<256, 256, 0, stream>>>(xb, wihb, bs, xg, xg32);
  lstm_persist<<<NBLK, 256, 0, stream>>>(whhb, xg, xg32, hb, bar,
                                         (float*)d_out);
}